// Round 5
// baseline (67.843 us; speedup 1.0000x reference)
//
#include <hip/hip_runtime.h>
#include <hip/hip_bf16.h>
#include <cstdint>

typedef __bf16 bf16_t;
typedef __attribute__((ext_vector_type(4))) __bf16 bf16x4;
typedef __attribute__((ext_vector_type(8))) __bf16 bf16x8;
typedef __attribute__((ext_vector_type(4))) float f32x4;

#define DIM 256
#define TINV 10.0f
// TINV * log2(e): e = exp(S/T) == exp2(S * EXP2C)
#define EXP2C 14.426950408889634f
#define BM 256
#define BN 256
#define BK 64

// Kernel 1: row-normalize y (f32) -> yn (bf16); zero the loss accumulator.
__global__ void nt_normalize(const float* __restrict__ y, bf16_t* __restrict__ yn,
                             float* __restrict__ out, int N) {
    int tid = threadIdx.x;
    int wave = tid >> 6, lane = tid & 63;
    int row = blockIdx.x * 4 + wave;
    float4 v = ((const float4*)(y + (size_t)row * DIM))[lane];
    float ss = v.x * v.x + v.y * v.y + v.z * v.z + v.w * v.w;
#pragma unroll
    for (int off = 1; off < 64; off <<= 1) ss += __shfl_xor(ss, off);
    float inv = 1.0f / fmaxf(sqrtf(ss), 1e-8f);
    bf16x4 o;
    o[0] = (bf16_t)(v.x * inv);
    o[1] = (bf16_t)(v.y * inv);
    o[2] = (bf16_t)(v.z * inv);
    o[3] = (bf16_t)(v.w * inv);
    ((bf16x4*)(yn + (size_t)row * DIM))[lane] = o;
    if (blockIdx.x == 0 && tid == 0) out[0] = 0.0f;   // zero loss accumulator
}

// Kernel 2: fused sim-GEMM + exp + partial row/col sums + pos capture.
// 256x256 tile (halves aggregate L2/L3 staging traffic vs 128^2: 135 MB vs 266 MB),
// triangular grid (by<=bx), 8 waves (2Mx4N), each wave 128x64 output.
// No global atomics: tile (by,bx) stores row-partials to P[bx][strip by] and
// (off-diag) col-partials to P[by][strip bx]; every P element has ONE writer.
// Single-buffer LDS, 2 barriers/K-iter (best measured structure).
__launch_bounds__(512, 2)
__global__ void nt_gemm(const bf16_t* __restrict__ yn, float* __restrict__ P,
                        float* __restrict__ posterm, int N) {
    const int nt = N / BN;                      // 32
    const int T = nt * (nt + 1) / 2;            // 528
    // bijective XCD-chunked swizzle (m204)
    int orig = blockIdx.x;
    int q = T >> 3, r = T & 7;
    int xcd = orig & 7, loc = orig >> 3;
    int t = (xcd < r ? xcd * (q + 1) : r * (q + 1) + (xcd - r) * q) + loc;
    // triangular index -> (by, bx), by <= bx (count from bottom-right corner)
    int s = T - 1 - t;
    float f = sqrtf(8.0f * (float)s + 1.0f);
    int j = (int)((f - 1.0f) * 0.5f);
    while ((j + 1) * (j + 2) / 2 <= s) ++j;
    while (j * (j + 1) / 2 > s) --j;
    int k = s - j * (j + 1) / 2;
    int by = nt - 1 - j, bx = nt - 1 - k;

    __shared__ __align__(16) bf16_t As[BM][BK];   // 32 KB
    __shared__ __align__(16) bf16_t Bs[BN][BK];   // 32 KB
    __shared__ float rowpart[4][BM];              // [wc][row-in-tile] 4 KB
    __shared__ float colpart[2][BN];              // [wr][col-in-tile] 2 KB

    int r0 = by * BM, c0 = bx * BN;
    int tid = threadIdx.x;
    int wave = tid >> 6, lane = tid & 63;
    int wr = wave >> 2, wc = wave & 3;            // 2 x 4 wave grid
    int l16 = lane & 15, lg = lane >> 4;

    f32x4 acc[8][4] = {};

    for (int k0 = 0; k0 < DIM; k0 += BK) {
        if (k0) __syncthreads();   // protect previous iter's LDS reads
        // Stage A,B tiles: 256x64 bf16 = 2048 16B-chunks each; 512 threads x 4 iters.
        // LDS chunk (row, cc) holds global chunk (row, cc ^ (row&7)).
#pragma unroll
        for (int it = 0; it < 4; ++it) {
            int cbase = it * 512 + wave * 64;     // wave-uniform chunk base
            int c = cbase + lane;                 // this lane's chunk
            int row = c >> 3, cc = c & 7;
            int gc = cc ^ (row & 7);
            const bf16_t* srcA = yn + (size_t)(r0 + row) * DIM + k0 + gc * 8;
            __builtin_amdgcn_global_load_lds(
                (const __attribute__((address_space(1))) uint32_t*)srcA,
                (__attribute__((address_space(3))) uint32_t*)((char*)&As[0][0] + cbase * 16),
                16, 0, 0);
            const bf16_t* srcB = yn + (size_t)(c0 + row) * DIM + k0 + gc * 8;
            __builtin_amdgcn_global_load_lds(
                (const __attribute__((address_space(1))) uint32_t*)srcB,
                (__attribute__((address_space(3))) uint32_t*)((char*)&Bs[0][0] + cbase * 16),
                16, 0, 0);
        }
        __syncthreads();   // drains vmcnt before any wave reads LDS

#pragma unroll
        for (int kk = 0; kk < 2; ++kk) {
            bf16x8 af[8], bfr[4];
#pragma unroll
            for (int m = 0; m < 8; ++m) {
                int row = wr * 128 + m * 16 + l16;
                int kc = kk * 4 + lg;
                af[m] = *(const bf16x8*)((const char*)&As[0][0] +
                                         row * (BK * 2) + ((kc ^ (row & 7)) * 16));
            }
#pragma unroll
            for (int n = 0; n < 4; ++n) {
                int row = wc * 64 + n * 16 + l16;
                int kc = kk * 4 + lg;
                bfr[n] = *(const bf16x8*)((const char*)&Bs[0][0] +
                                          row * (BK * 2) + ((kc ^ (row & 7)) * 16));
            }
#pragma unroll
            for (int m = 0; m < 8; ++m)
#pragma unroll
                for (int n = 0; n < 4; ++n)
                    acc[m][n] = __builtin_amdgcn_mfma_f32_16x16x32_bf16(
                        af[m], bfr[n], acc[m][n], 0, 0, 0);
        }
    }

    // Epilogue. C/D layout (m89): col = lane&15, row = (lane>>4)*4 + reg.
    // grow = r0 + wr*128 + m*16 + lg*4 + r2 ; gcol = c0 + wc*64 + n*16 + l16.
    bool diag = (by == bx);
    float colacc[4] = {0.0f, 0.0f, 0.0f, 0.0f};
#pragma unroll
    for (int m = 0; m < 8; ++m) {
#pragma unroll
        for (int r2 = 0; r2 < 4; ++r2) {
            int lrow = wr * 128 + m * 16 + lg * 4 + r2;   // row within tile
            int grow = r0 + lrow;
            float ssum = 0.0f;
#pragma unroll
            for (int n = 0; n < 4; ++n) {
                float S = acc[m][n][r2];
                float e = __builtin_amdgcn_exp2f(S * EXP2C);
                if (diag) {
                    int gcol = c0 + wc * 64 + n * 16 + l16;
                    if (gcol == grow) e = 0.0f;                        // mask diagonal
                    if (gcol == (grow ^ 1)) posterm[grow] = -S * TINV; // positive pair
                }
                ssum += e;
                colacc[n] += e;
            }
            ssum += __shfl_xor(ssum, 1);
            ssum += __shfl_xor(ssum, 2);
            ssum += __shfl_xor(ssum, 4);
            ssum += __shfl_xor(ssum, 8);
            if (l16 == 0) rowpart[wc][lrow] = ssum;
        }
    }
    // col partials: reduce across lg (xor 16/32 covers this wave's 128 rows)
#pragma unroll
    for (int n = 0; n < 4; ++n) {
        colacc[n] += __shfl_xor(colacc[n], 16);
        colacc[n] += __shfl_xor(colacc[n], 32);
    }
    if (!diag && lane < 16) {
#pragma unroll
        for (int n = 0; n < 4; ++n)
            colpart[wr][wc * 64 + n * 16 + lane] = colacc[n];
    }
    __syncthreads();
    // Combined single-writer stores: threads 0..255 -> row sums, 256..511 -> col sums.
    if (tid < BM) {
        float rsum = rowpart[0][tid] + rowpart[1][tid] + rowpart[2][tid] + rowpart[3][tid];
        P[(size_t)bx * N + r0 + tid] = rsum;
    } else if (!diag) {
        int lcol = tid - BM;
        P[(size_t)by * N + c0 + lcol] = colpart[0][lcol] + colpart[1][lcol];
    }
}

// Kernel 3: loss partial = sum over rows of (posterm[r] + log(sum_slots P[s][r]));
// one row per thread; one atomicAdd per block.
__global__ void nt_reduce(const float* __restrict__ P, const float* __restrict__ posterm,
                          float* __restrict__ out, int N, int nt) {
    int row = blockIdx.x * 256 + threadIdx.x;
    float s = 0.0f;
    for (int j = 0; j < nt; ++j) s += P[(size_t)j * N + row];
    float v = posterm[row] + logf(s);
#pragma unroll
    for (int off = 1; off < 64; off <<= 1) v += __shfl_xor(v, off);
    __shared__ float part[4];
    int wave = threadIdx.x >> 6, lane = threadIdx.x & 63;
    if (lane == 0) part[wave] = v;
    __syncthreads();
    if (threadIdx.x == 0) {
        float tot = part[0] + part[1] + part[2] + part[3];
        atomicAdd(out, tot / (float)N);
    }
}

extern "C" void kernel_launch(void* const* d_in, const int* in_sizes, int n_in,
                              void* d_out, int out_size, void* d_ws, size_t ws_size,
                              hipStream_t stream) {
    const float* y = (const float*)d_in[0];
    int N = in_sizes[0] / DIM;                 // 8192
    int nt = N / BN;                           // 32
    bf16_t* yn = (bf16_t*)d_ws;                // N*DIM bf16 = 4 MB
    float* posterm = (float*)((char*)d_ws + (size_t)N * DIM * sizeof(bf16_t));  // 32 KB
    float* P = posterm + N;                    // nt*N f32 = 1 MB
    float* out = (float*)d_out;

    nt_normalize<<<N / 4, 256, 0, stream>>>(y, yn, out, N);
    int T = nt * (nt + 1) / 2;                 // 528 blocks, no dead work
    nt_gemm<<<T, 512, 0, stream>>>(yn, P, posterm, N);
    nt_reduce<<<N / 256, 256, 0, stream>>>(P, posterm, out, N, nt);
}